// Round 10
// baseline (133.220 us; speedup 1.0000x reference)
//
#include <hip/hip_runtime.h>
#include <math.h>

#define R_ROUTES 1152
#define N_CAPS 10
#define C_IN 8
#define D_DIM 16
#define B_BATCH 128
#define JD 160                      // N_CAPS * D_DIM
#define KK 9216                     // R_ROUTES * C_IN (GEMM K)
#define KSPLIT 48                   // 24 routes = 192 k per split
#define RS 24                       // routes per k-split
#define NG 5                        // jd groups of 32
#define BH 2                        // batch halves
#define NBLK (KSPLIT * NG * BH)     // 480 blocks per iter grid

typedef __attribute__((ext_vector_type(8))) short short8;   // 8 bf16 (4 VGPRs)
typedef __attribute__((ext_vector_type(4))) float f32x4;    // MFMA accumulator

__device__ inline unsigned short f2bf(float f) {            // RNE fp32 -> bf16
    unsigned int u = __float_as_uint(f);
    unsigned int r = u + 0x7FFFu + ((u >> 16) & 1u);
    return (unsigned short)(r >> 16);
}
__device__ inline float bf2f(unsigned short h) {
    return __uint_as_float(((unsigned int)h) << 16);
}

// ---------------------------------------------------------------------------
// ws layout (byte offsets):
//   s0   fp32 [128][160]       @ 0        (81920)
//   s1   fp32 [128][160]       @ 81920    (81920)
//   s2   fp32 [128][160]       @ 163840   (81920)  [s0..s2 zeroed in d1]
//   cnt  u32                   @ 245760   (zeroed in d1; pad to 256)
//   b_ij fp32 [1152][10]       @ 246016   (46080; stored by va1, += by va2)
//   ctab fp32 [1152][10]       @ 292096   (46080; softmax(b) by k_va)
//   xT   bf16 [9216][128]      @ 338176   (2359296; M2 A-operand)
// Lesson log:
//  R13 (redundant agreement), R15 (ACQ-spin barrier): 10-40us poison each.
//  R16/R17 (111.6/112.0 == R0 112.2): three 7-dispatch internals tie ->
//    total = ~60us kernels + 6 x ~8us dispatch boundaries.
//  R18/R19 (176/152): full-K = few blocks -> W-fetch + serial-chain bound.
//  R20 (115.2): W-warm NEUTRAL-negative -> downstream kernels were never
//    fetch-bound (L2/L3 warm within a replay). Fetch theory dead.
//  R14 re-audit: last-block tail poison (+22us/dispatch) attributed to
//    __threadfence() per block = L2 writeback/invalidate x480 on 8-XCD
//    gfx950 (same mechanism as R15's spin poison). Counter + agent loads
//    never isolated. Semantics were verified correct (R14 passed).
//  R21 (this): ISOLATED test, 7 -> 6 dispatches: k_rs_final folds into
//    iter3 as a FENCE-FREE last-block tail: __syncthreads (drains vmcnt)
//    -> release fetch_add on cnt (orders s-atomics, no cache maintenance)
//    -> last block: relaxed agent loads, 256-thread parallel squash -> out.
//    All else bit-identical to R16/R17. Predict ~103-107; if ~115+, the
//    fence wasn't the poison and last-block tails are dead for good.
// ---------------------------------------------------------------------------

// d1: blocks 0..287 transpose x -> xT; 288..347 zero s0+s1+s2 (+cnt)
__global__ __launch_bounds__(256) void k_prep0(
    const float* __restrict__ x, unsigned short* __restrict__ xT,
    f32x4* __restrict__ zbase, unsigned int* __restrict__ cnt) {
    __shared__ float tile[32][33];
    int id = blockIdx.x, t = threadIdx.x;
    if (id < 288) {                           // ---- transpose role ----
        int bx = id;                          // rc tile 0..287
        int tx = t & 31, ty = t >> 5;
        for (int by = 0; by < 4; by++) {
            if (by) __syncthreads();
#pragma unroll
            for (int i = 0; i < 4; i++) {
                int row = ty + i * 8;         // b_local
                tile[row][tx] = x[(size_t)(by * 32 + row) * KK + bx * 32 + tx];
            }
            __syncthreads();
#pragma unroll
            for (int i = 0; i < 4; i++) {
                int row = ty + i * 8;         // rc_local
                xT[(size_t)(bx * 32 + row) * B_BATCH + by * 32 + tx] = f2bf(tile[tx][row]);
            }
        }
        return;
    }
    // ---- zero role: s0..s2 = 15360 f32x4 over 60 blocks; block 288 -> cnt
    int idx = (id - 288) * 256 + t;
    zbase[idx] = (f32x4){0.f, 0.f, 0.f, 0.f};
    if (id == 288 && t == 0) *cnt = 0u;
}

// One routing iteration's weighted-sum GEMM (R16/R17-verified, atomic path).
// No LDS in main path, no barriers. B-fragments built from global W in regs
// (fragment route rl = st*4+quad), A from x fp32 hi/lo split. atomicAdd -> s.
// LAST: fence-free last-block tail squashes s -> out (replaces k_rs_final).
template <int FIRST, int LAST>
__global__ __launch_bounds__(256) void k_iter(
    const float* __restrict__ x, const float* __restrict__ W,
    const float* __restrict__ ctab, float* __restrict__ s,
    unsigned int* __restrict__ cnt, float* __restrict__ out) {
    __shared__ unsigned int lastflag;
    int t = threadIdx.x;
    int ks = blockIdx.x, ng = blockIdx.y, bh = blockIdx.z;
    int r0 = ks * RS, jd0 = ng * 32, b_base = bh * 64;
    int w = t >> 6, l = t & 63, row = l & 15, quad = l >> 4;
    const float* px = x + (size_t)(b_base + w * 16 + row) * KK + ks * 192;
    f32x4 acc0 = {0,0,0,0}, acc1 = {0,0,0,0};
#pragma unroll
    for (int st = 0; st < 6; st++) {          // K = 192 = 6 steps of 32
        int rr = r0 + st * 4 + quad;          // route of this fragment
        float c0 = FIRST ? 0.1f : ctab[rr * N_CAPS + (jd0 >> 4)];
        float c1 = FIRST ? 0.1f : ctab[rr * N_CAPS + (jd0 >> 4) + 1];
        const float4* wp0 = (const float4*)(W + ((size_t)rr * JD + jd0 + row) * C_IN);
        const float4* wp1 = (const float4*)(W + ((size_t)rr * JD + jd0 + 16 + row) * C_IN);
        float4 wa = wp0[0], wb = wp0[1], wc = wp1[0], wd = wp1[1];
        float wv0[8] = {wa.x,wa.y,wa.z,wa.w, wb.x,wb.y,wb.z,wb.w};
        float wv1[8] = {wc.x,wc.y,wc.z,wc.w, wd.x,wd.y,wd.z,wd.w};
        short8 Bh0, Bh1;
#pragma unroll
        for (int i = 0; i < 8; i++) {
            Bh0[i] = (short)f2bf(wv0[i] * c0);
            Bh1[i] = (short)f2bf(wv1[i] * c1);
        }
        float4 x0 = *(const float4*)(px + st * 32 + quad * 8);
        float4 x1 = *(const float4*)(px + st * 32 + quad * 8 + 4);
        float xv[8] = {x0.x,x0.y,x0.z,x0.w, x1.x,x1.y,x1.z,x1.w};
        short8 Ah, Al;
#pragma unroll
        for (int i = 0; i < 8; i++) {
            unsigned short h = f2bf(xv[i]);
            Ah[i] = (short)h;
            Al[i] = (short)f2bf(xv[i] - bf2f(h));
        }
        acc0 = __builtin_amdgcn_mfma_f32_16x16x32_bf16(Ah, Bh0, acc0, 0, 0, 0);
        acc0 = __builtin_amdgcn_mfma_f32_16x16x32_bf16(Al, Bh0, acc0, 0, 0, 0);
        acc1 = __builtin_amdgcn_mfma_f32_16x16x32_bf16(Ah, Bh1, acc1, 0, 0, 0);
        acc1 = __builtin_amdgcn_mfma_f32_16x16x32_bf16(Al, Bh1, acc1, 0, 0, 0);
    }
#pragma unroll
    for (int i = 0; i < 4; i++) {             // C/D: col=lane&15 (jd), row=quad*4+i (b)
        int b0 = b_base + w * 16 + quad * 4 + i;
        atomicAdd(&s[(size_t)b0 * JD + jd0 + row],      acc0[i]);
        atomicAdd(&s[(size_t)b0 * JD + jd0 + 16 + row], acc1[i]);
    }

    if (LAST) {
        // Fence-free last-block tail. __syncthreads drains all waves' vmem
        // (compiler emits s_waitcnt vmcnt(0) before s_barrier); RELEASE on
        // the counter RMW orders the s-atomics at the coherence point; the
        // last block's ACQ side covers the reads. NO __threadfence -> no
        // per-block L2 writeback/invalidate storm (the R14 poison).
        __syncthreads();
        if (t == 0) {
            unsigned int old = __hip_atomic_fetch_add(
                cnt, 1u, __ATOMIC_ACQ_REL, __HIP_MEMORY_SCOPE_AGENT);
            lastflag = (old == (unsigned)(NBLK - 1)) ? 1u : 0u;
        }
        __syncthreads();
        if (lastflag) {
            // parallel squash: 256 threads x 5 (b,j) pairs, relaxed agent loads
#pragma unroll
            for (int q = 0; q < 5; q++) {
                int pi = t * 5 + q;           // (b, j) pair, 1280 total
                int b = pi / N_CAPS, j = pi % N_CAPS;
                const float* sp = s + (size_t)b * JD + j * D_DIM;
                float sv[D_DIM], sqn = 0.f;
#pragma unroll
                for (int d = 0; d < D_DIM; d++) {
                    sv[d] = __hip_atomic_load(sp + d, __ATOMIC_RELAXED,
                                              __HIP_MEMORY_SCOPE_AGENT);
                    sqn = fmaf(sv[d], sv[d], sqn);
                }
                float scale = sqn / ((1.f + sqn) * sqrtf(sqn));
#pragma unroll
                for (int d = 0; d < D_DIM; d++)
                    out[(size_t)b * JD + j * D_DIM + d] = sv[d] * scale;
            }
        }
    }
}

// Agreement + softmax (verified R16/R17): squash(s_prev)->vb, M2 via MFMA
// with in-register W contract, b_new for block's 4 routes, softmax -> ctab.
// ACCUM=0 (va1): b_ij = upd (store).  ACCUM=1 (va2): b_ij + upd.
template <int ACCUM>
__global__ __launch_bounds__(256) void k_va(
    const unsigned short* __restrict__ xT, const float* __restrict__ s_prev,
    const float* __restrict__ W, float* __restrict__ b_ij,
    float* __restrict__ ctab) {
    __shared__ unsigned short vb[JD][136];    // [jd][b], +8 pad (43520 B)
    __shared__ float bnew[4][N_CAPS];
    int t = threadIdx.x;
    int r0 = blockIdx.x * 4, rc0 = blockIdx.x * 32;

    // --- squash(s_prev) -> vb --------------------------------------------
#pragma unroll
    for (int q = 0; q < 5; q++) {
        int pi = t * 5 + q;                   // (b, j) pair, 1280 total
        int b = pi / N_CAPS, j = pi % N_CAPS;
        const float4* sp4 = (const float4*)(s_prev + (size_t)b * JD + j * D_DIM);
        float4 a0 = sp4[0], a1 = sp4[1], a2 = sp4[2], a3 = sp4[3];
        float sv[D_DIM] = {a0.x,a0.y,a0.z,a0.w, a1.x,a1.y,a1.z,a1.w,
                           a2.x,a2.y,a2.z,a2.w, a3.x,a3.y,a3.z,a3.w};
        float sqn = 0.f;
#pragma unroll
        for (int d = 0; d < D_DIM; d++) sqn = fmaf(sv[d], sv[d], sqn);
        float scale = sqn / ((1.f + sqn) * sqrtf(sqn));
#pragma unroll
        for (int d = 0; d < D_DIM; d++)
            vb[j * D_DIM + d][b] = f2bf(sv[d] * scale);
    }
    __syncthreads();

    int w = t >> 6, l = t & 63, row = l & 15, quad = l >> 4;
    int rhalf = l >> 5, cbase = (quad & 1) * 4;

    // --- M2 tiles + in-register W contract, 5 tiles/wave -----------------
#pragma unroll
    for (int jt = 0; jt < 5; jt++) {          // u = jt*4 + w
        int u = jt * 4 + w;
        int mt = u / 10, nt = u % 10;
        const short8* pa = (const short8*)(xT + (size_t)(rc0 + mt * 16 + row) * B_BATCH);
        f32x4 acc = {0, 0, 0, 0};
#pragma unroll
        for (int st = 0; st < 4; st++)        // K = 128 = 4 steps of 32
            acc = __builtin_amdgcn_mfma_f32_16x16x32_bf16(
                pa[st * 4 + quad],
                *(const short8*)&vb[nt * 16 + row][st * 32 + quad * 8],
                acc, 0, 0, 0);
        int r = r0 + 2 * mt + rhalf;
        const float* wp = W + ((size_t)r * JD + nt * 16 + row) * C_IN + cbase;
        float4 w4 = *(const float4*)wp;
        float part = acc[0]*w4.x + acc[1]*w4.y + acc[2]*w4.z + acc[3]*w4.w;
#pragma unroll
        for (int off = 1; off < 32; off <<= 1) part += __shfl_xor(part, off, 32);
        if ((l & 31) == 0) bnew[2 * mt + rhalf][nt] = part * (1.f / (float)B_BATCH);
    }
    __syncthreads();

    // --- softmax for this block's 4 routes -> ctab (and b_ij chain) ------
    if (t < 4) {
        float bj[N_CAPS], m = -1e30f;
#pragma unroll
        for (int j = 0; j < N_CAPS; j++) {
            float base = ACCUM ? b_ij[(r0 + t) * N_CAPS + j] : 0.f;
            bj[j] = base + bnew[t][j];
            m = fmaxf(m, bj[j]);
        }
        if (!ACCUM) {
#pragma unroll
            for (int j = 0; j < N_CAPS; j++) b_ij[(r0 + t) * N_CAPS + j] = bj[j];
        }
        float sum = 0.f;
#pragma unroll
        for (int j = 0; j < N_CAPS; j++) { bj[j] = expf(bj[j] - m); sum += bj[j]; }
        float inv = 1.f / sum;
#pragma unroll
        for (int j = 0; j < N_CAPS; j++) ctab[(r0 + t) * N_CAPS + j] = bj[j] * inv;
    }
}

extern "C" void kernel_launch(void* const* d_in, const int* in_sizes, int n_in,
                              void* d_out, int out_size, void* d_ws, size_t ws_size,
                              hipStream_t stream) {
    const float* x = (const float*)d_in[0];   // [128,1152,8]
    const float* W = (const float*)d_in[1];   // [1,1152,10,16,8]
    float* out = (float*)d_out;               // [128,10,16,1]
    char* ws = (char*)d_ws;

    float*          s0   = (float*)(ws + 0);
    float*          s1   = (float*)(ws + 81920);
    float*          s2   = (float*)(ws + 163840);
    unsigned int*   cnt  = (unsigned int*)(ws + 245760);
    float*          b_ij = (float*)(ws + 246016);
    float*          ctab = (float*)(ws + 292096);
    unsigned short* xT   = (unsigned short*)(ws + 338176);

    // d1: transpose x->xT + zero s0..s2, cnt
    k_prep0<<<348, 256, 0, stream>>>(x, xT, (f32x4*)ws, cnt);

    // d2: iter1 (c=0.1) -> s0 (atomic)
    k_iter<1, 0><<<dim3(KSPLIT, NG, BH), 256, 0, stream>>>(
        x, W, nullptr, s0, nullptr, nullptr);

    // d3: va1 -> b_ij (store), ctab
    k_va<0><<<288, 256, 0, stream>>>(xT, s0, W, b_ij, ctab);

    // d4: iter2 -> s1 (atomic)
    k_iter<0, 0><<<dim3(KSPLIT, NG, BH), 256, 0, stream>>>(
        x, W, ctab, s1, nullptr, nullptr);

    // d5: va2 -> ctab (b_ij + upd2)
    k_va<1><<<288, 256, 0, stream>>>(xT, s1, W, b_ij, ctab);

    // d6: iter3 -> s2 (atomic) + fence-free last-block squash -> out
    k_iter<0, 1><<<dim3(KSPLIT, NG, BH), 256, 0, stream>>>(
        x, W, ctab, s2, cnt, out);
}

// Round 11
// 126.237 us; speedup vs baseline: 1.0553x; 1.0553x over previous
//
#include <hip/hip_runtime.h>
#include <math.h>

#define R_ROUTES 1152
#define N_CAPS 10
#define C_IN 8
#define D_DIM 16
#define B_BATCH 128
#define JD 160                      // N_CAPS * D_DIM
#define KK 9216                     // R_ROUTES * C_IN (GEMM K)
#define KSPLIT 96                   // 12 routes = 96 k per split
#define RS 12                       // routes per k-split
#define NG 5                        // jd groups of 32
#define BH 2                        // batch halves

typedef __attribute__((ext_vector_type(8))) short short8;   // 8 bf16 (4 VGPRs)
typedef __attribute__((ext_vector_type(4))) float f32x4;    // MFMA accumulator

__device__ inline unsigned short f2bf(float f) {            // RNE fp32 -> bf16
    unsigned int u = __float_as_uint(f);
    unsigned int r = u + 0x7FFFu + ((u >> 16) & 1u);
    return (unsigned short)(r >> 16);
}
__device__ inline float bf2f(unsigned short h) {
    return __uint_as_float(((unsigned int)h) << 16);
}

// ---------------------------------------------------------------------------
// ws layout (byte offsets):
//   s0   fp32 [128][160]       @ 0        (81920)
//   s1   fp32 [128][160]       @ 81920    (81920)
//   s2   fp32 [128][160]       @ 163840   (81920)  [s0..s2 zeroed in d1]
//   b_ij fp32 [1152][10]       @ 245760   (46080; stored by va1, += by va2)
//   ctab fp32 [1152][10]       @ 291840   (46080; softmax(b) by k_va)
//   xT   bf16 [9216][128]      @ 337920   (2359296; M2 A-operand)
// Lesson log:
//  R13/R14/R15/R21: ALL in-kernel cross-block coordination is poison
//    (10-40us): redundant agreement, threadfence tails, ACQ-spin barriers,
//    and (R21, 133us) even a FENCE-FREE release-counter tail (+21us) -> the
//    per-block agent-scope acquire/release RMW itself is the storm. Closed.
//  R16/R17 (111.6/112.0 == R0 112.2): three 7-dispatch internals tie.
//  R18/R19 (176/152): full-K = few blocks, long chains. R20 (115): W-warm
//    neutral -> not fetch-bound.
//  MODEL: total = 7 kernels (~60us; iter/va ~10-13 each, latency-bound at
//    MfmaUtil 3%, Occ 12%) + 6 gaps (~8us). Remaining lever: per-kernel
//    critical path x parallelism.
//  R22 (this): same 7-dispatch chain, 2x grid parallelism everywhere:
//    - k_iter KSPLIT 48->96: dependent-MFMA chain 12->6, 960 blocks.
//    - k_va 288->576 blocks (2 routes, 1 m-tile): A-frags hoisted, 2-3
//      tiles/wave vs 5.
//    - prep: per-tile transpose (1152 thin blocks).
//  PRE-COMMIT: if >=108us, kernels are launch-floor-bound -> 7-dispatch
//    structural floor reached; declare done.
// ---------------------------------------------------------------------------

// d1: blocks 0..1151 transpose one 32x32 tile each; 1152..1211 zero s0..s2
__global__ __launch_bounds__(256) void k_prep0(
    const float* __restrict__ x, unsigned short* __restrict__ xT,
    f32x4* __restrict__ zbase) {
    __shared__ float tile[32][33];
    int id = blockIdx.x, t = threadIdx.x;
    if (id < 1152) {                          // ---- transpose role ----
        int bx = id % 288, by = id / 288;     // rc tile, b tile
        int tx = t & 31, ty = t >> 5;
#pragma unroll
        for (int i = 0; i < 4; i++) {
            int row = ty + i * 8;             // b_local
            tile[row][tx] = x[(size_t)(by * 32 + row) * KK + bx * 32 + tx];
        }
        __syncthreads();
#pragma unroll
        for (int i = 0; i < 4; i++) {
            int row = ty + i * 8;             // rc_local
            xT[(size_t)(bx * 32 + row) * B_BATCH + by * 32 + tx] = f2bf(tile[tx][row]);
        }
        return;
    }
    // ---- zero role: s0..s2 = 15360 f32x4 over 60 blocks ----
    int idx = (id - 1152) * 256 + t;
    zbase[idx] = (f32x4){0.f, 0.f, 0.f, 0.f};
}

// One routing iteration's weighted-sum GEMM (R16/R17-verified math, KSPLIT=96).
// No LDS, no barriers. B-fragments built from global W in regs (fragment
// route rr = r0 + st*4 + quad), A from x fp32 hi/lo split. atomicAdd -> s.
template <int FIRST>
__global__ __launch_bounds__(256) void k_iter(
    const float* __restrict__ x, const float* __restrict__ W,
    const float* __restrict__ ctab, float* __restrict__ s) {
    int t = threadIdx.x;
    int ks = blockIdx.x, ng = blockIdx.y, bh = blockIdx.z;
    int r0 = ks * RS, jd0 = ng * 32, b_base = bh * 64;
    int w = t >> 6, l = t & 63, row = l & 15, quad = l >> 4;
    const float* px = x + (size_t)(b_base + w * 16 + row) * KK + ks * 96;
    f32x4 acc0 = {0,0,0,0}, acc1 = {0,0,0,0};
#pragma unroll
    for (int st = 0; st < 3; st++) {          // K = 96 = 3 steps of 32
        int rr = r0 + st * 4 + quad;          // route of this fragment
        float c0 = FIRST ? 0.1f : ctab[rr * N_CAPS + (jd0 >> 4)];
        float c1 = FIRST ? 0.1f : ctab[rr * N_CAPS + (jd0 >> 4) + 1];
        const float4* wp0 = (const float4*)(W + ((size_t)rr * JD + jd0 + row) * C_IN);
        const float4* wp1 = (const float4*)(W + ((size_t)rr * JD + jd0 + 16 + row) * C_IN);
        float4 wa = wp0[0], wb = wp0[1], wc = wp1[0], wd = wp1[1];
        float wv0[8] = {wa.x,wa.y,wa.z,wa.w, wb.x,wb.y,wb.z,wb.w};
        float wv1[8] = {wc.x,wc.y,wc.z,wc.w, wd.x,wd.y,wd.z,wd.w};
        short8 Bh0, Bh1;
#pragma unroll
        for (int i = 0; i < 8; i++) {
            Bh0[i] = (short)f2bf(wv0[i] * c0);
            Bh1[i] = (short)f2bf(wv1[i] * c1);
        }
        float4 x0 = *(const float4*)(px + st * 32 + quad * 8);
        float4 x1 = *(const float4*)(px + st * 32 + quad * 8 + 4);
        float xv[8] = {x0.x,x0.y,x0.z,x0.w, x1.x,x1.y,x1.z,x1.w};
        short8 Ah, Al;
#pragma unroll
        for (int i = 0; i < 8; i++) {
            unsigned short h = f2bf(xv[i]);
            Ah[i] = (short)h;
            Al[i] = (short)f2bf(xv[i] - bf2f(h));
        }
        acc0 = __builtin_amdgcn_mfma_f32_16x16x32_bf16(Ah, Bh0, acc0, 0, 0, 0);
        acc0 = __builtin_amdgcn_mfma_f32_16x16x32_bf16(Al, Bh0, acc0, 0, 0, 0);
        acc1 = __builtin_amdgcn_mfma_f32_16x16x32_bf16(Ah, Bh1, acc1, 0, 0, 0);
        acc1 = __builtin_amdgcn_mfma_f32_16x16x32_bf16(Al, Bh1, acc1, 0, 0, 0);
    }
#pragma unroll
    for (int i = 0; i < 4; i++) {             // C/D: col=lane&15 (jd), row=quad*4+i (b)
        int b0 = b_base + w * 16 + quad * 4 + i;
        atomicAdd(&s[(size_t)b0 * JD + jd0 + row],      acc0[i]);
        atomicAdd(&s[(size_t)b0 * JD + jd0 + 16 + row], acc1[i]);
    }
}

// Agreement + softmax (verified math, 2 routes/block): squash(s_prev)->vb,
// M2 (1 m-tile) via MFMA with hoisted A-frags + in-register W contract,
// softmax -> ctab.  ACCUM=0 (va1): b_ij = upd.  ACCUM=1 (va2): b_ij + upd.
template <int ACCUM>
__global__ __launch_bounds__(256) void k_va(
    const unsigned short* __restrict__ xT, const float* __restrict__ s_prev,
    const float* __restrict__ W, float* __restrict__ b_ij,
    float* __restrict__ ctab) {
    __shared__ unsigned short vb[JD][136];    // [jd][b], +8 pad (43520 B)
    __shared__ float bnew[2][N_CAPS];
    int t = threadIdx.x;
    int r0 = blockIdx.x * 2, rc0 = blockIdx.x * 16;

    // --- squash(s_prev) -> vb --------------------------------------------
#pragma unroll
    for (int q = 0; q < 5; q++) {
        int pi = t * 5 + q;                   // (b, j) pair, 1280 total
        int b = pi / N_CAPS, j = pi % N_CAPS;
        const float4* sp4 = (const float4*)(s_prev + (size_t)b * JD + j * D_DIM);
        float4 a0 = sp4[0], a1 = sp4[1], a2 = sp4[2], a3 = sp4[3];
        float sv[D_DIM] = {a0.x,a0.y,a0.z,a0.w, a1.x,a1.y,a1.z,a1.w,
                           a2.x,a2.y,a2.z,a2.w, a3.x,a3.y,a3.z,a3.w};
        float sqn = 0.f;
#pragma unroll
        for (int d = 0; d < D_DIM; d++) sqn = fmaf(sv[d], sv[d], sqn);
        float scale = sqn / ((1.f + sqn) * sqrtf(sqn));
#pragma unroll
        for (int d = 0; d < D_DIM; d++)
            vb[j * D_DIM + d][b] = f2bf(sv[d] * scale);
    }
    __syncthreads();

    int w = t >> 6, l = t & 63, row = l & 15, quad = l >> 4;
    int rhalf = l >> 5, cbase = (quad & 1) * 4;

    // --- M2 (single m-tile) + in-register W contract ---------------------
    // A-fragments shared across all nt: hoisted. acc[i] = M2[rc=quad*4+i]
    // [jd=nt*16+row]; route = r0+rhalf, c = cbase+i; reduce over 32-lane half.
    const short8* pa = (const short8*)(xT + (size_t)(rc0 + row) * B_BATCH);
    short8 af0 = pa[quad], af1 = pa[4 + quad], af2 = pa[8 + quad], af3 = pa[12 + quad];
    for (int nt = w; nt < N_CAPS; nt += 4) {  // 2-3 tiles per wave
        f32x4 acc = {0, 0, 0, 0};
        acc = __builtin_amdgcn_mfma_f32_16x16x32_bf16(
            af0, *(const short8*)&vb[nt * 16 + row][quad * 8], acc, 0, 0, 0);
        acc = __builtin_amdgcn_mfma_f32_16x16x32_bf16(
            af1, *(const short8*)&vb[nt * 16 + row][32 + quad * 8], acc, 0, 0, 0);
        acc = __builtin_amdgcn_mfma_f32_16x16x32_bf16(
            af2, *(const short8*)&vb[nt * 16 + row][64 + quad * 8], acc, 0, 0, 0);
        acc = __builtin_amdgcn_mfma_f32_16x16x32_bf16(
            af3, *(const short8*)&vb[nt * 16 + row][96 + quad * 8], acc, 0, 0, 0);
        int r = r0 + rhalf;
        const float* wp = W + ((size_t)r * JD + nt * 16 + row) * C_IN + cbase;
        float4 w4 = *(const float4*)wp;
        float part = acc[0]*w4.x + acc[1]*w4.y + acc[2]*w4.z + acc[3]*w4.w;
#pragma unroll
        for (int off = 1; off < 32; off <<= 1) part += __shfl_xor(part, off, 32);
        if ((l & 31) == 0) bnew[rhalf][nt] = part * (1.f / (float)B_BATCH);
    }
    __syncthreads();

    // --- softmax for this block's 2 routes -> ctab (and b_ij chain) ------
    if (t < 2) {
        float bj[N_CAPS], m = -1e30f;
#pragma unroll
        for (int j = 0; j < N_CAPS; j++) {
            float base = ACCUM ? b_ij[(r0 + t) * N_CAPS + j] : 0.f;
            bj[j] = base + bnew[t][j];
            m = fmaxf(m, bj[j]);
        }
        if (!ACCUM) {
#pragma unroll
            for (int j = 0; j < N_CAPS; j++) b_ij[(r0 + t) * N_CAPS + j] = bj[j];
        }
        float sum = 0.f;
#pragma unroll
        for (int j = 0; j < N_CAPS; j++) { bj[j] = expf(bj[j] - m); sum += bj[j]; }
        float inv = 1.f / sum;
#pragma unroll
        for (int j = 0; j < N_CAPS; j++) ctab[(r0 + t) * N_CAPS + j] = bj[j] * inv;
    }
}

// final: squash s2 -> out (verified)
__global__ __launch_bounds__(320) void k_rs_final(
    const float* __restrict__ s, float* __restrict__ out) {
    int t = threadIdx.x;                      // 320 = 2 b x 160 jd
    int bloc = t / JD, jd = t % JD;
    int b = blockIdx.x * 2 + bloc;
    float acc = s[(size_t)b * JD + jd];
    float sq = acc * acc;                     // lane%16 == jd%16 -> width-16 xor
#pragma unroll
    for (int off = 1; off < 16; off <<= 1) sq += __shfl_xor(sq, off, 16);
    float scale = sq / ((1.f + sq) * sqrtf(sq));
    out[(size_t)b * JD + jd] = acc * scale;
}

extern "C" void kernel_launch(void* const* d_in, const int* in_sizes, int n_in,
                              void* d_out, int out_size, void* d_ws, size_t ws_size,
                              hipStream_t stream) {
    const float* x = (const float*)d_in[0];   // [128,1152,8]
    const float* W = (const float*)d_in[1];   // [1,1152,10,16,8]
    float* out = (float*)d_out;               // [128,10,16,1]
    char* ws = (char*)d_ws;

    float*          s0   = (float*)(ws + 0);
    float*          s1   = (float*)(ws + 81920);
    float*          s2   = (float*)(ws + 163840);
    float*          b_ij = (float*)(ws + 245760);
    float*          ctab = (float*)(ws + 291840);
    unsigned short* xT   = (unsigned short*)(ws + 337920);

    // d1: transpose x->xT (per-tile blocks) + zero s0..s2
    k_prep0<<<1212, 256, 0, stream>>>(x, xT, (f32x4*)ws);

    // d2: iter1 (c=0.1) -> s0
    k_iter<1><<<dim3(KSPLIT, NG, BH), 256, 0, stream>>>(x, W, nullptr, s0);

    // d3: va1 -> b_ij (store), ctab
    k_va<0><<<576, 256, 0, stream>>>(xT, s0, W, b_ij, ctab);

    // d4: iter2 -> s1
    k_iter<0><<<dim3(KSPLIT, NG, BH), 256, 0, stream>>>(x, W, ctab, s1);

    // d5: va2 -> ctab (b_ij + upd2)
    k_va<1><<<576, 256, 0, stream>>>(xT, s1, W, b_ij, ctab);

    // d6: iter3 -> s2
    k_iter<0><<<dim3(KSPLIT, NG, BH), 256, 0, stream>>>(x, W, ctab, s2);

    // d7: final squash
    k_rs_final<<<64, 320, 0, stream>>>(s2, out);
}

// Round 12
// 112.396 us; speedup vs baseline: 1.1853x; 1.1231x over previous
//
#include <hip/hip_runtime.h>
#include <math.h>

#define R_ROUTES 1152
#define N_CAPS 10
#define C_IN 8
#define D_DIM 16
#define B_BATCH 128
#define JD 160                      // N_CAPS * D_DIM
#define KK 9216                     // R_ROUTES * C_IN (GEMM K)
#define KSPLIT 48                   // 24 routes = 192 k per split
#define RS 24                       // routes per k-split
#define NG 5                        // jd groups of 32
#define BH 2                        // batch halves
#define NBLK (KSPLIT * NG * BH)     // 480 blocks per iter grid

typedef __attribute__((ext_vector_type(8))) short short8;   // 8 bf16 (4 VGPRs)
typedef __attribute__((ext_vector_type(4))) float f32x4;    // MFMA accumulator

__device__ inline unsigned short f2bf(float f) {            // RNE fp32 -> bf16
    unsigned int u = __float_as_uint(f);
    unsigned int r = u + 0x7FFFu + ((u >> 16) & 1u);
    return (unsigned short)(r >> 16);
}
__device__ inline float bf2f(unsigned short h) {
    return __uint_as_float(((unsigned int)h) << 16);
}

// ---------------------------------------------------------------------------
// FINAL KERNEL — restoration of R16 (best verified: 111.6us).
// ws layout (byte offsets):
//   s0/s1/s2 fp32 [128][160]   @ 0        (3x81920, ends 245760)
//   b_ij fp32 [1152][10]       @ 245760   (46080; stored by va1, += by va2)
//   ctab fp32 [1152][10]       @ 291840   (46080; softmax(b) written by k_va)
//   xT   bf16 [9216][128]      @ 337920   (2359296; M2 A-operand)
// ---------------------------------------------------------------------------
// SESSION CONCLUSION (R0-R22): 112us is the structural floor on this harness.
//   - Kernel internals: R0/R16/R17, three different implementations
//     (LDS-staged, reg-built-B, split-K-store) tie at 112 +/- 0.4us.
//   - Dispatch count: 7 is the floor. Every reduction mechanism regressed:
//     R13 redundant per-block agreement (+40), R14 threadfence last-block
//     tail (+65), R15 agent ACQ-spin chunk barrier (+36), R18/R19 full-K
//     fewer-dispatch chain (+64/+40), R21 fence-free release-counter tail
//     (+21; the per-block agent-scope RMW itself is the cache storm).
//   - Parallelism: R12 2x waves neutral; R22 2x blocks -14us WORSE (fixed
//     dispatch cost dominates; more blocks = more ramp + 2x atomics).
//   - Atomics exonerated (R10/R11); HBM-fetch warming neutral (R20).
//   Arithmetic floor: 7 dispatches x ~8us fixed + ~55us latency-bound
//   micro-kernels (3 GFLOP / 40MB cannot fill 256 CUs) ~= 110us. We're there.
// ---------------------------------------------------------------------------

__global__ __launch_bounds__(256) void k_zero(f32x4* __restrict__ p) {
    int i = blockIdx.x * 256 + threadIdx.x;   // 20 blocks: 5120 f32x4 = s0
    p[i] = (f32x4){0.f, 0.f, 0.f, 0.f};
}

// Shared GEMM body: one routing iteration's weighted-sum GEMM.
// No LDS, no barriers: per step st, fragment route rl = st*4+quad;
// B built from W*c in regs, A from x fp32 hi/lo split. atomicAdd into s.
template <bool FIRST>
__device__ inline void iter_body(
    const float* __restrict__ x, const float* __restrict__ W,
    const float* __restrict__ ctab, float* __restrict__ s,
    int ks, int ng, int bh, int t) {
    int r0 = ks * RS, jd0 = ng * 32, b_base = bh * 64;
    int w = t >> 6, l = t & 63, row = l & 15, quad = l >> 4;
    const float* px = x + (size_t)(b_base + w * 16 + row) * KK + ks * 192;
    f32x4 acc0 = {0,0,0,0}, acc1 = {0,0,0,0};
#pragma unroll
    for (int st = 0; st < 6; st++) {          // K = 192 = 6 steps of 32
        int rr = r0 + st * 4 + quad;          // route of this fragment
        float c0 = FIRST ? 0.1f : ctab[rr * N_CAPS + (jd0 >> 4)];
        float c1 = FIRST ? 0.1f : ctab[rr * N_CAPS + (jd0 >> 4) + 1];
        const float4* wp0 = (const float4*)(W + ((size_t)rr * JD + jd0 + row) * C_IN);
        const float4* wp1 = (const float4*)(W + ((size_t)rr * JD + jd0 + 16 + row) * C_IN);
        float4 wa = wp0[0], wb = wp0[1], wc = wp1[0], wd = wp1[1];
        float wv0[8] = {wa.x,wa.y,wa.z,wa.w, wb.x,wb.y,wb.z,wb.w};
        float wv1[8] = {wc.x,wc.y,wc.z,wc.w, wd.x,wd.y,wd.z,wd.w};
        short8 Bh0, Bh1;
#pragma unroll
        for (int i = 0; i < 8; i++) {
            Bh0[i] = (short)f2bf(wv0[i] * c0);
            Bh1[i] = (short)f2bf(wv1[i] * c1);
        }
        float4 x0 = *(const float4*)(px + st * 32 + quad * 8);
        float4 x1 = *(const float4*)(px + st * 32 + quad * 8 + 4);
        float xv[8] = {x0.x,x0.y,x0.z,x0.w, x1.x,x1.y,x1.z,x1.w};
        short8 Ah, Al;
#pragma unroll
        for (int i = 0; i < 8; i++) {
            unsigned short h = f2bf(xv[i]);
            Ah[i] = (short)h;
            Al[i] = (short)f2bf(xv[i] - bf2f(h));
        }
        acc0 = __builtin_amdgcn_mfma_f32_16x16x32_bf16(Ah, Bh0, acc0, 0, 0, 0);
        acc0 = __builtin_amdgcn_mfma_f32_16x16x32_bf16(Al, Bh0, acc0, 0, 0, 0);
        acc1 = __builtin_amdgcn_mfma_f32_16x16x32_bf16(Ah, Bh1, acc1, 0, 0, 0);
        acc1 = __builtin_amdgcn_mfma_f32_16x16x32_bf16(Al, Bh1, acc1, 0, 0, 0);
    }
#pragma unroll
    for (int i = 0; i < 4; i++) {             // C/D: col=lane&15 (jd), row=quad*4+i (b)
        int b0 = b_base + w * 16 + quad * 4 + i;
        atomicAdd(&s[(size_t)b0 * JD + jd0 + row],      acc0[i]);
        atomicAdd(&s[(size_t)b0 * JD + jd0 + 16 + row], acc1[i]);
    }
}

// Dispatch 2: blocks 0..479 iter1 (c=0.1); 480..767 transpose x->xT;
//             768..807 zero s1/s2 (not read until dispatch 4/6).
__global__ __launch_bounds__(256) void k_first(
    const float* __restrict__ x, const float* __restrict__ W,
    unsigned short* __restrict__ xT, float* __restrict__ s0,
    f32x4* __restrict__ z12) {
    __shared__ float tile[32][33];
    int id = blockIdx.x, t = threadIdx.x;

    if (id < NBLK) {                          // ---- iter1 role ----
        iter_body<true>(x, W, nullptr, s0, id % KSPLIT, (id / KSPLIT) % NG,
                        id / (KSPLIT * NG), t);
        return;
    }
    if (id < NBLK + 288) {                    // ---- transpose role ----
        int bx = id - NBLK;                   // rc tile 0..287
        int tx = t & 31, ty = t >> 5;
        for (int by = 0; by < 4; by++) {
            if (by) __syncthreads();
#pragma unroll
            for (int i = 0; i < 4; i++) {
                int row = ty + i * 8;         // b_local
                tile[row][tx] = x[(size_t)(by * 32 + row) * KK + bx * 32 + tx];
            }
            __syncthreads();
#pragma unroll
            for (int i = 0; i < 4; i++) {
                int row = ty + i * 8;         // rc_local
                xT[(size_t)(bx * 32 + row) * B_BATCH + by * 32 + tx] = f2bf(tile[tx][row]);
            }
        }
        return;
    }
    // ---- zero role: s1+s2 = 10240 f32x4 over 40 blocks ----
    int idx = (id - (NBLK + 288)) * 256 + t;
    z12[idx] = (f32x4){0.f, 0.f, 0.f, 0.f};
}

// Standalone iteration GEMM (iter2/iter3), grid (48,5,2).
__global__ __launch_bounds__(256) void k_iter(
    const float* __restrict__ x, const float* __restrict__ W,
    const float* __restrict__ ctab, float* __restrict__ s) {
    iter_body<false>(x, W, ctab, s, blockIdx.x, blockIdx.y, blockIdx.z,
                     threadIdx.x);
}

// Agreement + softmax: squash(s_prev)->vb, M2 via MFMA with in-register W
// contract (no m2 LDS), b_new for this block's 4 routes, softmax -> ctab.
// ACCUM=0 (va1): b_ij = upd (store; no zeroing needed).
// ACCUM=1 (va2): b_ij + upd (no store back; last use).
template <int ACCUM>
__global__ __launch_bounds__(256) void k_va(
    const unsigned short* __restrict__ xT, const float* __restrict__ s_prev,
    const float* __restrict__ W, float* __restrict__ b_ij,
    float* __restrict__ ctab) {
    __shared__ unsigned short vb[JD][136];    // [jd][b], +8 pad (43520 B)
    __shared__ float bnew[4][N_CAPS];
    int t = threadIdx.x;
    int r0 = blockIdx.x * 4, rc0 = blockIdx.x * 32;

    // --- squash(s_prev) -> vb --------------------------------------------
#pragma unroll
    for (int q = 0; q < 5; q++) {
        int pi = t * 5 + q;                   // (b, j) pair, 1280 total
        int b = pi / N_CAPS, j = pi % N_CAPS;
        const float4* sp4 = (const float4*)(s_prev + (size_t)b * JD + j * D_DIM);
        float4 a0 = sp4[0], a1 = sp4[1], a2 = sp4[2], a3 = sp4[3];
        float sv[D_DIM] = {a0.x,a0.y,a0.z,a0.w, a1.x,a1.y,a1.z,a1.w,
                           a2.x,a2.y,a2.z,a2.w, a3.x,a3.y,a3.z,a3.w};
        float sqn = 0.f;
#pragma unroll
        for (int d = 0; d < D_DIM; d++) sqn = fmaf(sv[d], sv[d], sqn);
        float scale = sqn / ((1.f + sqn) * sqrtf(sqn));
#pragma unroll
        for (int d = 0; d < D_DIM; d++)
            vb[j * D_DIM + d][b] = f2bf(sv[d] * scale);
    }
    __syncthreads();

    int w = t >> 6, l = t & 63, row = l & 15, quad = l >> 4;
    int rhalf = l >> 5, cbase = (quad & 1) * 4;

    // --- M2 tiles + in-register W contract (verified R13/R15) -----------
    // tile (mt,nt): acc[i] = M2[rc=mt*16+quad*4+i][jd=nt*16+row];
    // route = r0+2mt+rhalf, c = cbase+i; reduce over 32-lane half.
    for (int u = w; u < 20; u += 4) {         // 5 tiles/wave
        int mt = u / 10, nt = u % 10;
        const short8* pa = (const short8*)(xT + (size_t)(rc0 + mt * 16 + row) * B_BATCH);
        f32x4 acc = {0,0,0,0};
#pragma unroll
        for (int st = 0; st < 4; st++)        // K = 128 = 4 steps of 32
            acc = __builtin_amdgcn_mfma_f32_16x16x32_bf16(
                pa[st * 4 + quad],
                *(const short8*)&vb[nt * 16 + row][st * 32 + quad * 8],
                acc, 0, 0, 0);
        int r = r0 + 2 * mt + rhalf;
        const float* wp = W + ((size_t)r * JD + nt * 16 + row) * C_IN + cbase;
        float4 w4 = *(const float4*)wp;
        float part = acc[0]*w4.x + acc[1]*w4.y + acc[2]*w4.z + acc[3]*w4.w;
#pragma unroll
        for (int off = 1; off < 32; off <<= 1) part += __shfl_xor(part, off, 32);
        if ((l & 31) == 0) bnew[2 * mt + rhalf][nt] = part * (1.f / (float)B_BATCH);
    }
    __syncthreads();

    // --- softmax for this block's 4 routes -> ctab (and b_ij chain) ------
    if (t < 4) {
        float bj[N_CAPS], m = -1e30f;
#pragma unroll
        for (int j = 0; j < N_CAPS; j++) {
            float base = ACCUM ? b_ij[(r0 + t) * N_CAPS + j] : 0.f;
            bj[j] = base + bnew[t][j];
            m = fmaxf(m, bj[j]);
        }
        if (!ACCUM) {
#pragma unroll
            for (int j = 0; j < N_CAPS; j++) b_ij[(r0 + t) * N_CAPS + j] = bj[j];
        }
        float sum = 0.f;
#pragma unroll
        for (int j = 0; j < N_CAPS; j++) { bj[j] = expf(bj[j] - m); sum += bj[j]; }
        float inv = 1.f / sum;
#pragma unroll
        for (int j = 0; j < N_CAPS; j++) ctab[(r0 + t) * N_CAPS + j] = bj[j] * inv;
    }
}

// final: squash s2 -> out
__global__ __launch_bounds__(320) void k_rs_final(
    const float* __restrict__ s, float* __restrict__ out) {
    int t = threadIdx.x;                      // 320 = 2 b x 160 jd
    int bloc = t / JD, jd = t % JD;
    int b = blockIdx.x * 2 + bloc;
    float acc = s[(size_t)b * JD + jd];
    float sq = acc * acc;                     // lane%16 == jd%16 -> width-16 xor
#pragma unroll
    for (int off = 1; off < 16; off <<= 1) sq += __shfl_xor(sq, off, 16);
    float scale = sq / ((1.f + sq) * sqrtf(sq));
    out[(size_t)b * JD + jd] = acc * scale;
}

extern "C" void kernel_launch(void* const* d_in, const int* in_sizes, int n_in,
                              void* d_out, int out_size, void* d_ws, size_t ws_size,
                              hipStream_t stream) {
    const float* x = (const float*)d_in[0];   // [128,1152,8]
    const float* W = (const float*)d_in[1];   // [1,1152,10,16,8]
    float* out = (float*)d_out;               // [128,10,16,1]
    char* ws = (char*)d_ws;

    float*          s0   = (float*)(ws + 0);
    float*          s1   = (float*)(ws + 81920);
    float*          s2   = (float*)(ws + 163840);
    float*          b_ij = (float*)(ws + 245760);
    float*          ctab = (float*)(ws + 291840);
    unsigned short* xT   = (unsigned short*)(ws + 337920);

    // d1: zero s0 (82KB)
    k_zero<<<20, 256, 0, stream>>>((f32x4*)s0);

    // d2: iter1 (c=0.1) + transpose x->xT + zero s1/s2
    k_first<<<808, 256, 0, stream>>>(x, W, xT, s0, (f32x4*)s1);

    // d3: va1 -> b_ij (store), ctab
    k_va<0><<<288, 256, 0, stream>>>(xT, s0, W, b_ij, ctab);

    // d4: iter2 -> s1
    k_iter<<<dim3(KSPLIT, NG, BH), 256, 0, stream>>>(x, W, ctab, s1);

    // d5: va2 -> ctab (b_ij + upd2)
    k_va<1><<<288, 256, 0, stream>>>(xT, s1, W, b_ij, ctab);

    // d6: iter3 -> s2
    k_iter<<<dim3(KSPLIT, NG, BH), 256, 0, stream>>>(x, W, ctab, s2);

    // d7: final squash
    k_rs_final<<<64, 320, 0, stream>>>(s2, out);
}